// Round 4
// baseline (438.084 us; speedup 1.0000x reference)
//
#include <hip/hip_runtime.h>
#include <hip/hip_bf16.h>

#define NN 8192
#define FF 64
#define JSPLIT 4
#define JRANGE (NN / JSPLIT)    // 2048 cols per block (4 waves x 512)
#define PROW 66                 // partial row stride (floats): H[0..63], l at [64]

typedef _Float16 half8 __attribute__((ext_vector_type(8)));
typedef _Float16 half4v __attribute__((ext_vector_type(4)));
typedef float f32x4 __attribute__((ext_vector_type(4)));
typedef float f32x4v __attribute__((ext_vector_type(4)));
typedef int i32x4 __attribute__((ext_vector_type(4)));

// ---------------------------------------------------------------------------
// Kernel 1: Wh = inputs @ W; s = Wh@a_src; d = Wh@a_dst; WhT fp16 (80 x NN:
// rows 0..63 = Wh^T, row 64 = ones, 65..79 = 0); per-block max(d) partial.
// ---------------------------------------------------------------------------
__global__ __launch_bounds__(256) void k_prep(const float* __restrict__ inp,
                                              const float* __restrict__ W,
                                              const float* __restrict__ a,
                                              _Float16* __restrict__ WhT,
                                              float* __restrict__ s,
                                              float* __restrict__ d,
                                              float* __restrict__ dmax_part)
{
    __shared__ float Wl[64][64];
    __shared__ float asrc[64], adst[64];
    __shared__ _Float16 tr[64][20];
    __shared__ float dmx[16];
    const int t = threadIdx.x;
    for (int idx = t; idx < 4096; idx += 256) Wl[idx >> 6][idx & 63] = W[idx];
    if (t < 64) { asrc[t] = a[t]; adst[t] = a[64 + t]; }
    __syncthreads();

    const int rowl = t >> 4;
    const int fg   = t & 15;
    const int row  = blockIdx.x * 16 + rowl;
    const float* ip = inp + (size_t)row * FF;

    float a0 = 0.f, a1 = 0.f, a2 = 0.f, a3 = 0.f;
    #pragma unroll
    for (int k4 = 0; k4 < 16; ++k4) {
        float4 x  = *(const float4*)(ip + k4 * 4);
        float4 w0 = *(const float4*)&Wl[k4 * 4 + 0][fg * 4];
        float4 w1 = *(const float4*)&Wl[k4 * 4 + 1][fg * 4];
        float4 w2 = *(const float4*)&Wl[k4 * 4 + 2][fg * 4];
        float4 w3 = *(const float4*)&Wl[k4 * 4 + 3][fg * 4];
        a0 += x.x * w0.x + x.y * w1.x + x.z * w2.x + x.w * w3.x;
        a1 += x.x * w0.y + x.y * w1.y + x.z * w2.y + x.w * w3.y;
        a2 += x.x * w0.z + x.y * w1.z + x.z * w2.z + x.w * w3.z;
        a3 += x.x * w0.w + x.y * w1.w + x.z * w2.w + x.w * w3.w;
    }

    float sp = a0 * asrc[fg*4] + a1 * asrc[fg*4+1] + a2 * asrc[fg*4+2] + a3 * asrc[fg*4+3];
    float dp = a0 * adst[fg*4] + a1 * adst[fg*4+1] + a2 * adst[fg*4+2] + a3 * adst[fg*4+3];
    #pragma unroll
    for (int msk = 1; msk < 16; msk <<= 1) {
        sp += __shfl_xor(sp, msk);
        dp += __shfl_xor(dp, msk);
    }
    if (fg == 0) { s[row] = sp; d[row] = dp; dmx[rowl] = dp; }

    tr[fg * 4 + 0][rowl] = (_Float16)a0;
    tr[fg * 4 + 1][rowl] = (_Float16)a1;
    tr[fg * 4 + 2][rowl] = (_Float16)a2;
    tr[fg * 4 + 3][rowl] = (_Float16)a3;
    __syncthreads();
    {
        const int f = t >> 2, seg = t & 3;
        *(half4v*)(WhT + (size_t)f * NN + blockIdx.x * 16 + seg * 4) =
            *(const half4v*)&tr[f][seg * 4];
        const int fr = 64 + (t >> 4);
        WhT[(size_t)fr * NN + blockIdx.x * 16 + (t & 15)] =
            (_Float16)(((t >> 4) == 0) ? 1.0f : 0.0f);
    }
    if (t == 0) {
        float mm = dmx[0];
        #pragma unroll
        for (int i = 1; i < 16; ++i) mm = fmaxf(mm, dmx[i]);
        dmax_part[blockIdx.x] = mm;
    }
}

// ---------------------------------------------------------------------------
// Kernel 2: dmax = max over 512 partials; c[i] = leakyrelu(s[i] + dmax).
// ---------------------------------------------------------------------------
__global__ __launch_bounds__(256) void k_shift(const float* __restrict__ s,
                                               const float* __restrict__ dmax_part,
                                               float* __restrict__ c)
{
    __shared__ float red[256];
    const int t = threadIdx.x;
    float m = fmaxf(dmax_part[t], dmax_part[t + 256]);
    red[t] = m;
    __syncthreads();
    for (int off = 128; off > 0; off >>= 1) {
        if (t < off) red[t] = fmaxf(red[t], red[t + off]);
        __syncthreads();
    }
    const float dmax = red[0];
    const int row = blockIdx.x * 256 + t;
    float x = s[row] + dmax;
    c[row] = fmaxf(x, 0.2f * x);
}

__device__ __forceinline__ half4v build4(float sv, float cv, i32x4 aa, f32x4v dd)
{
    float e0 = sv + dd[0]; e0 = fmaxf(e0, 0.2f * e0);
    float e1 = sv + dd[1]; e1 = fmaxf(e1, 0.2f * e1);
    float e2 = sv + dd[2]; e2 = fmaxf(e2, 0.2f * e2);
    float e3 = sv + dd[3]; e3 = fmaxf(e3, 0.2f * e3);
    float p0 = (aa[0] > 0) ? __expf(e0 - cv) : 0.0f;
    float p1 = (aa[1] > 0) ? __expf(e1 - cv) : 0.0f;
    float p2 = (aa[2] > 0) ? __expf(e2 - cv) : 0.0f;
    float p3 = (aa[3] > 0) ? __expf(e3 - cv) : 0.0f;
    half4v r;
    r[0] = (_Float16)p0; r[1] = (_Float16)p1;
    r[2] = (_Float16)p2; r[3] = (_Float16)p3;
    return r;
}

// ---------------------------------------------------------------------------
// Kernel 3 (main): 2048 blocks = 512 row-tiles x 4 j-splits; 4 waves per
// block each own an independent 16-row x 512-col strip. NO LDS staging, NO
// barriers in the K-loop: each lane loads its own adj row slice straight to
// registers (nt, fully line-utilized), 1-iter-deep register prefetch lets
// the compiler emit fine-grained vmcnt overlap. 8 iters x 64 cols.
// ---------------------------------------------------------------------------
__global__ __launch_bounds__(256, 3) void k_main(const int* __restrict__ adj,
                                                 const _Float16* __restrict__ WhT,
                                                 const float* __restrict__ s,
                                                 const float* __restrict__ c,
                                                 const float* __restrict__ dv,
                                                 float* __restrict__ part)
{
    __shared__ float red[4][16][66];

    const int tid  = threadIdx.x;
    const int wv   = tid >> 6;
    const int lane = tid & 63;
    const int m    = lane & 15;
    const int g    = lane >> 4;
    const int rt   = blockIdx.x >> 2;
    const int js   = blockIdx.x & 3;
    const int i0   = rt * 16;
    const int row  = i0 + m;
    const int jw   = js * JRANGE + wv * 512 + g * 8;  // lane's starting col

    const float sv = s[row];
    const float cv = c[row];

    const int*      ap = adj + (size_t)row * NN + jw;
    const float*    dp = dv + jw;
    const _Float16* bp = WhT + (size_t)m * NN + jw;

    f32x4 acc[5];
    #pragma unroll
    for (int n = 0; n < 5; ++n) acc[n] = (f32x4){0.f, 0.f, 0.f, 0.f};

    // ---- prefetch iteration 0 into registers
    i32x4  na0 = __builtin_nontemporal_load((const i32x4*)ap);
    i32x4  na1 = __builtin_nontemporal_load((const i32x4*)(ap + 4));
    i32x4  na2 = __builtin_nontemporal_load((const i32x4*)(ap + 32));
    i32x4  na3 = __builtin_nontemporal_load((const i32x4*)(ap + 36));
    f32x4v nd0 = *(const f32x4v*)(dp);
    f32x4v nd1 = *(const f32x4v*)(dp + 4);
    f32x4v nd2 = *(const f32x4v*)(dp + 32);
    f32x4v nd3 = *(const f32x4v*)(dp + 36);

    for (int it = 0; it < 8; ++it) {
        i32x4  a0 = na0, a1 = na1, a2 = na2, a3 = na3;
        f32x4v d0 = nd0, d1 = nd1, d2 = nd2, d3 = nd3;
        if (it < 7) {                       // prefetch next iter (uniform branch)
            ap += 64; dp += 64;
            na0 = __builtin_nontemporal_load((const i32x4*)ap);
            na1 = __builtin_nontemporal_load((const i32x4*)(ap + 4));
            na2 = __builtin_nontemporal_load((const i32x4*)(ap + 32));
            na3 = __builtin_nontemporal_load((const i32x4*)(ap + 36));
            nd0 = *(const f32x4v*)(dp);
            nd1 = *(const f32x4v*)(dp + 4);
            nd2 = *(const f32x4v*)(dp + 32);
            nd3 = *(const f32x4v*)(dp + 36);
        }

        half4v lo0 = build4(sv, cv, a0, d0);
        half4v hi0 = build4(sv, cv, a1, d1);
        half4v lo1 = build4(sv, cv, a2, d2);
        half4v hi1 = build4(sv, cv, a3, d3);
        half8 Af0 = __builtin_shufflevector(lo0, hi0, 0, 1, 2, 3, 4, 5, 6, 7);
        half8 Af1 = __builtin_shufflevector(lo1, hi1, 0, 1, 2, 3, 4, 5, 6, 7);

        const _Float16* bq = bp + it * 64;
        #pragma unroll
        for (int n = 0; n < 5; ++n) {
            half8 B0 = *(const half8*)(bq + (size_t)n * 16 * NN);
            half8 B1 = *(const half8*)(bq + (size_t)n * 16 * NN + 32);
            acc[n] = __builtin_amdgcn_mfma_f32_16x16x32_f16(Af0, B0, acc[n], 0, 0, 0);
            acc[n] = __builtin_amdgcn_mfma_f32_16x16x32_f16(Af1, B1, acc[n], 0, 0, 0);
        }
    }

    // ---- cross-wave combine into fp32 partial ----
    #pragma unroll
    for (int n = 0; n < 4; ++n)
        #pragma unroll
        for (int r = 0; r < 4; ++r)
            red[wv][g * 4 + r][n * 16 + m] = acc[n][r];
    if (m == 0) {
        #pragma unroll
        for (int r = 0; r < 4; ++r)
            red[wv][g * 4 + r][64] = acc[4][r];
    }
    __syncthreads();

    float* pb = part + (size_t)blockIdx.x * (16 * PROW);
    const int col = tid & 63;
    const int r0  = tid >> 6;
    #pragma unroll
    for (int rr = 0; rr < 4; ++rr) {
        const int rl = r0 * 4 + rr;
        pb[rl * PROW + col] = red[0][rl][col] + red[1][rl][col] +
                              red[2][rl][col] + red[3][rl][col];
    }
    if (tid < 16) {
        pb[tid * PROW + 64] = red[0][tid][64] + red[1][tid][64] +
                              red[2][tid][64] + red[3][tid][64];
    }
}

// ---------------------------------------------------------------------------
// Kernel 4: combine 4 j-split partials, divide by l, ELU, write out.
// ---------------------------------------------------------------------------
__global__ __launch_bounds__(256) void k_reduce(const float* __restrict__ part,
                                                float* __restrict__ out)
{
    const int rt  = blockIdx.x;
    const int col = threadIdx.x & 63;
    const int r0  = threadIdx.x >> 6;
    const float* pb = part + (size_t)rt * 4 * (16 * PROW);
    #pragma unroll
    for (int rr = 0; rr < 4; ++rr) {
        const int rl = r0 * 4 + rr;
        float h = 0.f, l = 0.f;
        #pragma unroll
        for (int j = 0; j < 4; ++j) {
            h += pb[(j * 16 + rl) * PROW + col];
            l += pb[(j * 16 + rl) * PROW + 64];
        }
        float v = h / l;
        out[(size_t)(rt * 16 + rl) * FF + col] = (v > 0.f) ? v : (__expf(v) - 1.0f);
    }
}

extern "C" void kernel_launch(void* const* d_in, const int* in_sizes, int n_in,
                              void* d_out, int out_size, void* d_ws, size_t ws_size,
                              hipStream_t stream)
{
    const float* inp = (const float*)d_in[0];
    const int*   adj = (const int*)d_in[1];
    const float* W   = (const float*)d_in[2];
    const float* a   = (const float*)d_in[3];
    float* out = (float*)d_out;

    char* ws = (char*)d_ws;
    _Float16* WhT = (_Float16*)ws;                           // 80*NN*2 = 1,310,720 B
    float* s    = (float*)(ws + (size_t)80 * NN * 2);        // 32 KB
    float* dv   = s + NN;                                    // 32 KB
    float* c    = dv + NN;                                   // 32 KB
    float* dmp  = c + NN;                                    // 512 floats
    float* part = dmp + 512;                                 // 2048*16*66*4 = 8.65 MB

    k_prep  <<<NN / 16, 256, 0, stream>>>(inp, W, a, WhT, s, dv, dmp);
    k_shift <<<32, 256, 0, stream>>>(s, dmp, c);
    k_main  <<<(NN / 16) * JSPLIT, 256, 0, stream>>>(adj, WhT, s, c, dv, part);
    k_reduce<<<NN / 16, 256, 0, stream>>>(part, out);
}